// Round 13
// baseline (614.162 us; speedup 1.0000x reference)
//
#include <hip/hip_runtime.h>
#include <hip/hip_fp16.h>
#include <math.h>

#define NN 50000
#define NE 800000
#define TT 6
#define HID 48
#define NB 196   // (NN+255)/256
#define XS 28    // node-major LDS row stride in u32 (112B, 16B-aligned, (7*lane+c)%8 quad-conflict-free)
#define AW 160   // A row stride in u32: 640B = 5 x 128B cachelines, every row line-aligned

__device__ __forceinline__ float sigmoidf_(float x){ return 1.0f/(1.0f+__expf(-x)); }
__device__ __forceinline__ float tanhf_(float x){
  float xc = fminf(fmaxf(x,-15.f),15.f);
  float t = __expf(2.f*xc);
  return (t-1.f)/(t+1.f);
}
__device__ __forceinline__ unsigned f2bf(float x){
  unsigned u = __float_as_uint(x);
  return (u + 0x7fffu + ((u>>16)&1u)) >> 16;   // RNE to bf16
}
__device__ __forceinline__ unsigned pack2(float a, float b){
  return f2bf(a) | (f2bf(b)<<16);
}
__device__ __forceinline__ float bflo(unsigned u){ return __uint_as_float(u<<16); }
__device__ __forceinline__ float bfhi(unsigned u){ return __uint_as_float(u & 0xffff0000u); }
__device__ __forceinline__ unsigned f2h(float x){
  return (unsigned)__half_as_ushort(__float2half(x));   // RNE fp16
}
__device__ __forceinline__ float h2f(unsigned u){
  return __half2float(__ushort_as_half((unsigned short)(u & 0xffffu)));
}
__device__ __forceinline__ unsigned pack2h(float a, float b){   // RNE fp16 pair
  return f2h(a) | (f2h(b)<<16);
}

typedef __fp16 h2t __attribute__((ext_vector_type(2)));

// acc += lo(a)*lo(b) + hi(a)*hi(b), fp32 accumulate
__device__ __forceinline__ float dot2f(unsigned a, unsigned b, float c){
#if __has_builtin(__builtin_amdgcn_fdot2)
  return __builtin_amdgcn_fdot2(__builtin_bit_cast(h2t, a), __builtin_bit_cast(h2t, b), c, false);
#else
  h2t av = __builtin_bit_cast(h2t, a), bv = __builtin_bit_cast(h2t, b);
  return c + (float)av[0]*(float)bv[0] + (float)av[1]*(float)bv[1];
#endif
}

struct U3 { unsigned x,y,z; };

// 256-thread inclusive block scan (4 waves of 64)
__device__ __forceinline__ int block_scan_incl(int x, int* wsum){
  int lane = threadIdx.x & 63, w = threadIdx.x >> 6;
  int v = x;
#pragma unroll
  for(int d=1; d<64; d<<=1){
    int u = __shfl_up(v, d, 64);
    if(lane >= d) v += u;
  }
  if(lane==63) wsum[w] = v;
  __syncthreads();
  int add = 0;
#pragma unroll
  for(int k=0;k<3;k++) if(w>k) add += wsum[k];
  return v + add;
}

// ---------------- setup: cnt init + GRU weight repack (fp16 pairs along k) ----------------
// W3 [16 w][24 k2][18 c] u32: wave w owns hidden features 3w..3w+2.
//   c<9 : h-side (Whh), cc=c:   cc<3 -> r-row (3w+cc), cc<6 -> z-row (48+3w+cc-3), else n-row (96+3w+cc-6)
//   c>=9: x-side (Wih), cc=c-9, same row map.
__global__ __launch_bounds__(256) void k_setup(int* cnt,
                                               const float* __restrict__ Wih, const float* __restrict__ Whh,
                                               unsigned* W3){
  int i = blockIdx.x*256+threadIdx.x;
  if(i<NN) cnt[i]=0;
  if(i < 16*24*18){
    int w = i/432, r = i%432;
    int k2 = r/18, c = r%18;
    int cc = (c<9)? c : (c-9);
    int row = (cc<3) ? (w*3 + cc) : (cc<6) ? (48 + w*3 + cc-3) : (96 + w*3 + cc-6);
    const float* Wsrc = (c<9)? Whh : Wih;
    W3[i] = pack2h(Wsrc[row*48 + 2*k2], Wsrc[row*48 + 2*k2 + 1]);
  }
}

// single atomic per edge: rank within destination bucket
__global__ __launch_bounds__(256) void k_cnt(const int* __restrict__ ei, int* cnt, int* pos){
  int e = blockIdx.x*256+threadIdx.x;
  if(e<NE){
    int c = ei[NE+e];
    pos[e] = atomicAdd(&cnt[c], 1);
  }
}

// phase A: per-block sums of cnt
__global__ __launch_bounds__(256) void k_partA(const int* __restrict__ cnt, int* bsum){
  __shared__ int wsum[4];
  int i = blockIdx.x*256+threadIdx.x;
  int x = (i<NN)? cnt[i] : 0;
  int lane = threadIdx.x & 63, w = threadIdx.x >> 6;
  int v = x;
#pragma unroll
  for(int m=32;m>=1;m>>=1) v += __shfl_xor(v, m, 64);
  if(lane==0) wsum[w]=v;
  __syncthreads();
  if(threadIdx.x==0) bsum[blockIdx.x] = wsum[0]+wsum[1]+wsum[2]+wsum[3];
}

// phase B: exclusive scan of 196 block sums
__global__ __launch_bounds__(256) void k_midB(const int* __restrict__ bsum, int* bpre, int* offs){
  __shared__ int wsum[4];
  int t = threadIdx.x;
  int x = (t<NB)? bsum[t] : 0;
  int incl = block_scan_incl(x, wsum);
  if(t<NB) bpre[t] = incl - x;
  if(t==255) offs[NN] = incl;   // total
}

// phase C: per-block exclusive scan of cnt + bpre -> offs
__global__ __launch_bounds__(256) void k_offsC(const int* __restrict__ cnt, const int* __restrict__ bpre,
                                               int* offs){
  __shared__ int wsum[4];
  int i = blockIdx.x*256+threadIdx.x;
  int x = (i<NN)? cnt[i] : 0;
  int incl = block_scan_incl(x, wsum);
  if(i<NN) offs[i] = bpre[blockIdx.x] + incl - x;
}

// atomic-free scatter: csr[offs[c]+pos[e]] = (row, ew)
__global__ __launch_bounds__(256) void k_scatter(const int* __restrict__ ei, const float* __restrict__ ew,
                                                 const int* __restrict__ offs, const int* __restrict__ pos,
                                                 int2* __restrict__ csr){
  int e = blockIdx.x*256+threadIdx.x;
  if(e<NE){
    int c = ei[NE+e];
    int2 v; v.x = ei[e]; v.y = __float_as_int(ew[e]);
    csr[offs[c]+pos[e]] = v;
  }
}

// deg = 1 + row-sum of ew (atomic-free), dis = rsqrt(deg)  [deg>=1 always]
__global__ __launch_bounds__(256) void k_deg(const int2* __restrict__ csr, const int* __restrict__ offs,
                                             float* dis){
  int i = blockIdx.x*256+threadIdx.x;
  if(i<NN){
    float s = 1.f;
    int e0=offs[i], e1=offs[i+1];
    for(int j=e0;j<e1;j++) s += __int_as_float(csr[j].y);
    dis[i] = rsqrtf(s);
  }
}

// patch edge norm in place: y = dis[r]*ew   (dis[c] factored out in k_agg)
__global__ __launch_bounds__(256) void k_normE(int2* __restrict__ csr, const float* __restrict__ dis){
  int j = blockIdx.x*256+threadIdx.x;
  if(j<NE){
    int2 v = csr[j];
    v.y = __float_as_int(dis[v.x]*__int_as_float(v.y));
    csr[j] = v;
  }
}

// ---------------- layer-0 matmul: wave = feature slice (uniform), lane = node ----------------
// t-OUTER loop (r8 win): per-wave L1 window 4 KB vs 24 KB.
// A row per node = AW=160 words (640B, line-aligned); data in words 0..143.
__global__ __launch_bounds__(256) void k_mm0(const float* __restrict__ X, const float* __restrict__ W,
                                             unsigned* __restrict__ A){
  int s = __builtin_amdgcn_readfirstlane(threadIdx.x>>6);   // 0..3, wave-uniform
  int n = blockIdx.x*64 + (threadIdx.x&63);
  if(n>=NN) return;
  const float* xb = X + (long long)n*64;
  const float* wb = W + 12*s;
  float acc[TT][12];
#pragma unroll
  for(int t=0;t<TT;t++)
#pragma unroll
    for(int j=0;j<12;j++) acc[t][j]=0.f;
#pragma unroll
  for(int t=0;t<TT;t++){                 // full unroll: acc[t] constant-indexed
    const float* xt = xb + (long long)t*NN*64;
#pragma unroll 2
    for(int k4=0;k4<16;k4++){
      float4 xv = *reinterpret_cast<const float4*>(xt + 4*k4);
#pragma unroll
      for(int q=0;q<4;q++){
        const float* wr = wb + (4*k4+q)*HID;
        float w[12];
#pragma unroll
        for(int j=0;j<12;j++) w[j]=wr[j];   // uniform addr -> s_load
        float xs = (&xv.x)[q];
#pragma unroll
        for(int j=0;j<12;j++) acc[t][j] = fmaf(xs, w[j], acc[t][j]);
      }
    }
  }
  unsigned buf[36];
#pragma unroll
  for(int j=0;j<12;j++){
    buf[3*j  ]=pack2(acc[0][j],acc[1][j]);
    buf[3*j+1]=pack2(acc[2][j],acc[3][j]);
    buf[3*j+2]=pack2(acc[4][j],acc[5][j]);
  }
  uint4* o4 = reinterpret_cast<uint4*>(A + (long long)n*AW + 36*s);
#pragma unroll
  for(int q=0;q<9;q++) o4[q] = make_uint4(buf[4*q],buf[4*q+1],buf[4*q+2],buf[4*q+3]);
}

// ---------------- layer-1 matmul (K=48), input fp32 [n][t][48], t-outer ----------------
__global__ __launch_bounds__(256) void k_mm1(const float* __restrict__ X, const float* __restrict__ W,
                                             unsigned* __restrict__ A){
  int s = __builtin_amdgcn_readfirstlane(threadIdx.x>>6);
  int n = blockIdx.x*64 + (threadIdx.x&63);
  if(n>=NN) return;
  const float* xb = X + (long long)n*(TT*HID);
  const float* wb = W + 12*s;
  float acc[TT][12];
#pragma unroll
  for(int t=0;t<TT;t++)
#pragma unroll
    for(int j=0;j<12;j++) acc[t][j]=0.f;
#pragma unroll
  for(int t=0;t<TT;t++){                 // full unroll: acc[t] constant-indexed
    const float* xt = xb + t*HID;
#pragma unroll 2
    for(int k4=0;k4<12;k4++){
      float4 xv = *reinterpret_cast<const float4*>(xt + 4*k4);
#pragma unroll
      for(int q=0;q<4;q++){
        const float* wr = wb + (4*k4+q)*HID;
        float w[12];
#pragma unroll
        for(int j=0;j<12;j++) w[j]=wr[j];
        float xs = (&xv.x)[q];
#pragma unroll
        for(int j=0;j<12;j++) acc[t][j] = fmaf(xs, w[j], acc[t][j]);
      }
    }
  }
  unsigned buf[36];
#pragma unroll
  for(int j=0;j<12;j++){
    buf[3*j  ]=pack2(acc[0][j],acc[1][j]);
    buf[3*j+1]=pack2(acc[2][j],acc[3][j]);
    buf[3*j+2]=pack2(acc[4][j],acc[5][j]);
  }
  uint4* o4 = reinterpret_cast<uint4*>(A + (long long)n*AW + 36*s);
#pragma unroll
  for(int q=0;q<9;q++) o4[q] = make_uint4(buf[4*q],buf[4*q+1],buf[4*q+2],buf[4*q+3]);
}

// ---------------- CSR aggregation (bf16 gather) + bias + LN + ReLU (+resid)
// Scalarized wave-uniform path (r11). A rows 640B line-aligned (r12).
// out   : optional fp32 [n][t][48] output (layer 0 -> h1, needed for resid+mm1)
// out_pk: optional packed-fp16 [n][t][24 u32] output (layer 1 -> h2p, feeds GRU directly)
__global__ __launch_bounds__(256) void k_agg(const unsigned* __restrict__ A, const float* __restrict__ bias,
                                             const float* __restrict__ gain, const float* __restrict__ beta,
                                             const float* __restrict__ resid, float* __restrict__ out,
                                             unsigned* __restrict__ out_pk,
                                             const int* __restrict__ offs, const int2* __restrict__ csr,
                                             const float* __restrict__ dis){
  int wid = (int)((blockIdx.x*256+threadIdx.x)>>6);
  wid = __builtin_amdgcn_readfirstlane(wid);            // wave-uniform -> scalar
  int lane = threadIdx.x & 63;
  if(wid>=NN) return;
  const bool act = lane<HID;
  const int f = act? lane : (HID-1);
  const unsigned* Arow = A + 3*f;                       // SGPR base + per-lane const
  float dn = dis[wid];                                  // scalar load
  float acc[TT];
  {
    U3 v = *reinterpret_cast<const U3*>(Arow + (long long)wid*AW);
    acc[0]=dn*bflo(v.x); acc[1]=dn*bfhi(v.x);
    acc[2]=dn*bflo(v.y); acc[3]=dn*bfhi(v.y);
    acc[4]=dn*bflo(v.z); acc[5]=dn*bfhi(v.z);
  }
  int e0=offs[wid], e1=offs[wid+1];                     // scalar loads
  int e=e0;
  for(; e+3<e1; e+=4){
    int2 i0=csr[e], i1=csr[e+1], i2=csr[e+2], i3=csr[e+3];   // scalar s_loads
    U3 d0 = *reinterpret_cast<const U3*>(Arow + (long long)i0.x*AW);
    U3 d1 = *reinterpret_cast<const U3*>(Arow + (long long)i1.x*AW);
    U3 d2 = *reinterpret_cast<const U3*>(Arow + (long long)i2.x*AW);
    U3 d3 = *reinterpret_cast<const U3*>(Arow + (long long)i3.x*AW);
    float n0=__int_as_float(i0.y), n1=__int_as_float(i1.y);
    float n2=__int_as_float(i2.y), n3=__int_as_float(i3.y);
    acc[0]=fmaf(n0,bflo(d0.x),acc[0]); acc[1]=fmaf(n0,bfhi(d0.x),acc[1]);
    acc[2]=fmaf(n0,bflo(d0.y),acc[2]); acc[3]=fmaf(n0,bfhi(d0.y),acc[3]);
    acc[4]=fmaf(n0,bflo(d0.z),acc[4]); acc[5]=fmaf(n0,bfhi(d0.z),acc[5]);
    acc[0]=fmaf(n1,bflo(d1.x),acc[0]); acc[1]=fmaf(n1,bfhi(d1.x),acc[1]);
    acc[2]=fmaf(n1,bflo(d1.y),acc[2]); acc[3]=fmaf(n1,bfhi(d1.y),acc[3]);
    acc[4]=fmaf(n1,bflo(d1.z),acc[4]); acc[5]=fmaf(n1,bfhi(d1.z),acc[5]);
    acc[0]=fmaf(n2,bflo(d2.x),acc[0]); acc[1]=fmaf(n2,bfhi(d2.x),acc[1]);
    acc[2]=fmaf(n2,bflo(d2.y),acc[2]); acc[3]=fmaf(n2,bfhi(d2.y),acc[3]);
    acc[4]=fmaf(n2,bflo(d2.z),acc[4]); acc[5]=fmaf(n2,bfhi(d2.z),acc[5]);
    acc[0]=fmaf(n3,bflo(d3.x),acc[0]); acc[1]=fmaf(n3,bfhi(d3.x),acc[1]);
    acc[2]=fmaf(n3,bflo(d3.y),acc[2]); acc[3]=fmaf(n3,bfhi(d3.y),acc[3]);
    acc[4]=fmaf(n3,bflo(d3.z),acc[4]); acc[5]=fmaf(n3,bfhi(d3.z),acc[5]);
  }
  for(; e<e1; ++e){
    int2 i0=csr[e];
    U3 d0 = *reinterpret_cast<const U3*>(Arow + (long long)i0.x*AW);
    float n0=__int_as_float(i0.y);
    acc[0]=fmaf(n0,bflo(d0.x),acc[0]); acc[1]=fmaf(n0,bfhi(d0.x),acc[1]);
    acc[2]=fmaf(n0,bflo(d0.y),acc[2]); acc[3]=fmaf(n0,bfhi(d0.y),acc[3]);
    acc[4]=fmaf(n0,bflo(d0.z),acc[4]); acc[5]=fmaf(n0,bfhi(d0.z),acc[5]);
  }
  float bb = bias[f], gg = gain[f], be = beta[f];
  const float rn = 1.0f/HID;
#pragma unroll
  for(int t=0;t<TT;t++){
    float val = fmaf(acc[t], dn, bb);    // final *dn fold
    float v = act? val : 0.f;
    float s = v, s2 = v*v;
#pragma unroll
    for(int m=32;m>=1;m>>=1){
      s  += __shfl_xor(s,  m, 64);
      s2 += __shfl_xor(s2, m, 64);
    }
    float mu  = s*rn;
    float var = fmaxf(s2*rn - mu*mu, 0.f);
    float y = (val-mu)*rsqrtf(var+1e-5f)*gg + be;
    y = fmaxf(y, 0.f);
    long long oidx = (long long)wid*(TT*HID) + t*HID + f;
    if(resid) y += resid[oidx];
    if(out){
      if(act) out[oidx] = y;
    }
    if(out_pk){
      float yn = __shfl_xor(y, 1, 64);   // pair feature f^1
      if(act && !(lane&1))
        out_pk[(long long)wid*144 + t*24 + (lane>>1)] = pack2h(y, yn);
    }
  }
}

// ---------------- fused GRU v6: 16 waves / 1024 threads -> 100% CU thread occupancy ----------
// block: 64 nodes, 1024 threads = 16 waves. Wave w owns hidden features 3w..3w+2 (9 gate rows).
// Same proven structure as v5 (2 x {3-step gi phase, 3-step rec phase}, node-major XS=28
// rows, conflict-free ds_read_b128, pure-SMEM ws[9] k-loops, per-side scalar set 13.8 KB
// sK$-resident). 2 blocks/CU = 2048 threads (v5's 768-thread blocks capped at 1536 = 75%).
// __launch_bounds__(1024,8) pins VGPR <= 64 so 8 waves/SIMD are guaranteed.
__global__ __launch_bounds__(1024, 8) void k_gruF6(const unsigned* __restrict__ Xp,  // h2 packed [n][144] u32
                                                   const unsigned* __restrict__ W3, // [16][24][18] u32
                                                   const float* __restrict__ bih, const float* __restrict__ bhh,
                                                   const float* __restrict__ Wc1, const float* __restrict__ bc1,
                                                   const float* __restrict__ Wc2, const float* __restrict__ bc2,
                                                   float* __restrict__ out){
  __shared__ __align__(16) unsigned xall[TT*64*XS];   // 42 KB
  __shared__ __align__(16) unsigned hb[2][64*XS];     // 14 KB  (56 KB total -> 2 blocks/CU)
  int tid = threadIdx.x;
  int wv = __builtin_amdgcn_readfirstlane(tid>>6);   // 0..15, uniform
  int lane = tid & 63;
  int f0 = wv*3;
  long long n = (long long)blockIdx.x*64 + lane;

  // stage x: thread (nd,q) copies node nd's uint2 chunk q for all 6 t (768 active threads)
  if(tid < 768){
    int nd = tid/12, q = tid-12*nd;
    long long g = (long long)blockIdx.x*64+nd; if(g>NN-1) g=NN-1;
    const unsigned* xs = Xp + g*144 + 2*q;
#pragma unroll
    for(int t=0;t<TT;t++){
      uint2 v = *reinterpret_cast<const uint2*>(xs + t*24);
      *reinterpret_cast<uint2*>(&xall[t*64*XS + nd*XS + 2*q]) = v;
    }
  }
  for(int i=tid;i<64*XS;i+=1024) hb[0][i]=0u;

  // biases are wave-uniform (per-feature, features per-wave) -> live in SGPRs
  float rbi[3], zbi[3], nbi[3], rbh[3], zbh[3], nbh[3], hprev[3];
#pragma unroll
  for(int j=0;j<3;j++){
    rbi[j]=bih[f0+j]; zbi[j]=bih[48+f0+j]; nbi[j]=bih[96+f0+j];
    rbh[j]=bhh[f0+j]; zbh[j]=bhh[48+f0+j]; nbh[j]=bhh[96+f0+j];
    hprev[j]=0.f;
  }
  __syncthreads();   // xall + hb[0] ready

  int cur=0;
#pragma unroll
  for(int tp=0; tp<2; tp++){
    // ---- phase 1: gi for steps 3tp..3tp+2 (x-side only, barrier-free) ----
    unsigned gp[15];   // 3 steps x 9 gate-values, fp16-packed (constant-indexed)
#pragma unroll
    for(int s=0;s<3;s++){
      float a[9];
#pragma unroll
      for(int j=0;j<3;j++){ a[j]=rbi[j]; a[3+j]=zbi[j]; a[6+j]=nbi[j]; }
      const uint4* xrow = reinterpret_cast<const uint4*>(&xall[(tp*3+s)*64*XS + lane*XS]);
      const unsigned* wbx = W3 + (wv*24)*18 + 9;   // x-slice base
#pragma unroll 2
      for(int c6=0;c6<6;c6++){
        uint4 hq = xrow[c6];                      // ds_read_b128, conflict-free
        unsigned xv_[4] = {hq.x, hq.y, hq.z, hq.w};
#pragma unroll
        for(int j4=0;j4<4;j4++){
          const unsigned* wp = wbx + (4*c6+j4)*18;
          unsigned ws[9];
#pragma unroll
          for(int q=0;q<9;q++) ws[q]=wp[q];       // uniform -> s_load
#pragma unroll
          for(int c=0;c<9;c++) a[c]=dot2f(xv_[j4], ws[c], a[c]);
        }
      }
      gp[5*s  ]=pack2h(a[0],a[1]); gp[5*s+1]=pack2h(a[2],a[3]);
      gp[5*s+2]=pack2h(a[4],a[5]); gp[5*s+3]=pack2h(a[6],a[7]);
      gp[5*s+4]=pack2h(a[8],0.f);
    }
    // ---- phase 2: 3 recurrence steps (h-weights sK$-resident, pure-SMEM k-loop) ----
#pragma unroll
    for(int s=0;s<3;s++){
      float acc[9];
#pragma unroll
      for(int j=0;j<3;j++){ acc[j]=rbh[j]; acc[3+j]=zbh[j]; acc[6+j]=nbh[j]; }
      const uint4* hrow = reinterpret_cast<const uint4*>(&hb[cur][lane*XS]);
      const unsigned* wbh = W3 + (wv*24)*18;       // h-slice base
#pragma unroll 2
      for(int c6=0;c6<6;c6++){
        uint4 hq = hrow[c6];                      // ds_read_b128, conflict-free
        unsigned hv_[4] = {hq.x, hq.y, hq.z, hq.w};
#pragma unroll
        for(int j4=0;j4<4;j4++){
          const unsigned* wp = wbh + (4*c6+j4)*18;
          unsigned ws[9];
#pragma unroll
          for(int q=0;q<9;q++) ws[q]=wp[q];       // uniform -> s_load
#pragma unroll
          for(int c=0;c<9;c++) acc[c]=dot2f(hv_[j4], ws[c], acc[c]);
        }
      }
      // unpack this step's gi (all indices compile-time)
      float g0_=h2f(gp[5*s  ]), g1_=h2f(gp[5*s  ]>>16);
      float g2_=h2f(gp[5*s+1]), g3_=h2f(gp[5*s+1]>>16);
      float g4_=h2f(gp[5*s+2]), g5_=h2f(gp[5*s+2]>>16);
      float g6_=h2f(gp[5*s+3]), g7_=h2f(gp[5*s+3]>>16);
      float g8_=h2f(gp[5*s+4]);
      float gr[3]={g0_,g1_,g2_}, gz[3]={g3_,g4_,g5_}, gn[3]={g6_,g7_,g8_};
      __half* hw16 = reinterpret_cast<__half*>(&hb[cur^1][0]) + lane*(2*XS) + f0;
      float hn[3];
#pragma unroll
      for(int j=0;j<3;j++){
        float r  = sigmoidf_(acc[j]   + gr[j]);
        float zg = sigmoidf_(acc[3+j] + gz[j]);
        float ng = tanhf_(gn[j] + r*acc[6+j]);
        float hv = (1.f-zg)*ng + zg*hprev[j];
        hprev[j]=hv; hn[j]=hv;
      }
#pragma unroll
      for(int j=0;j<3;j++) hw16[j] = __float2half(hn[j]);   // 3x ds_write_b16 (RNE)
      __syncthreads();   // next buffer fully written
      cur^=1;
    }
  }

  // classifier epilogue: wave 0 covers the block's 64 nodes
  if(wv==0 && n<NN){
    unsigned hh[24];
    {
      const uint4* hrow = reinterpret_cast<const uint4*>(&hb[cur][lane*XS]);
#pragma unroll
      for(int c6=0;c6<6;c6++){
        uint4 v = hrow[c6];
        hh[4*c6]=v.x; hh[4*c6+1]=v.y; hh[4*c6+2]=v.z; hh[4*c6+3]=v.w;
      }
    }
    float hv[24];
#pragma unroll
    for(int j=0;j<24;j++) hv[j]=bc1[j];
#pragma unroll 2
    for(int k2=0;k2<24;k2++){
      float hk0 = h2f(hh[k2]), hk1 = h2f(hh[k2]>>16);
      const float* w0 = Wc1 + (2*k2)*24;     // uniform -> s_load
      const float* w1 = Wc1 + (2*k2+1)*24;
#pragma unroll
      for(int j=0;j<24;j++) hv[j] = fmaf(hk0, w0[j], hv[j]);
#pragma unroll
      for(int j=0;j<24;j++) hv[j] = fmaf(hk1, w1[j], hv[j]);
    }
    float l0=bc2[0], l1=bc2[1];
#pragma unroll
    for(int j=0;j<24;j++){
      float a = fmaxf(hv[j],0.f);
      l0 = fmaf(a, Wc2[2*j],   l0);
      l1 = fmaf(a, Wc2[2*j+1], l1);
    }
    reinterpret_cast<float2*>(out)[n] = make_float2(l0,l1);
  }
}

static inline size_t al256(size_t x){ return (x+255)&~(size_t)255; }

extern "C" void kernel_launch(void* const* d_in, const int* in_sizes, int n_in,
                              void* d_out, int out_size, void* d_ws, size_t ws_size,
                              hipStream_t stream){
  const float* x_seq=(const float*)d_in[0];
  const int*   ei   =(const int*)d_in[1];
  const float* ew   =(const float*)d_in[2];
  const float* W0=(const float*)d_in[3];  const float* b0=(const float*)d_in[4];
  const float* g0=(const float*)d_in[5];  const float* be0=(const float*)d_in[6];
  const float* W1=(const float*)d_in[7];  const float* b1=(const float*)d_in[8];
  const float* g1=(const float*)d_in[9];  const float* be1=(const float*)d_in[10];
  const float* Wih=(const float*)d_in[11];const float* Whh=(const float*)d_in[12];
  const float* bih=(const float*)d_in[13];const float* bhh=(const float*)d_in[14];
  const float* Wc1=(const float*)d_in[15];const float* bc1=(const float*)d_in[16];
  const float* Wc2=(const float*)d_in[17];const float* bc2=(const float*)d_in[18];
  float* outp=(float*)d_out;

  char* p=(char*)d_ws; size_t off=0;
  auto alloc=[&](size_t bytes)->void*{ void* r=p+off; off=al256(off+bytes); return r; };
  float* dis    =(float*)alloc((size_t)NN*4);
  int*   cnt    =(int*)  alloc((size_t)NN*4);
  int*   offs   =(int*)  alloc((size_t)(NN+1)*4);
  int*   bsum   =(int*)  alloc((size_t)NB*4);
  int*   bpre   =(int*)  alloc((size_t)NB*4);
  int*   pos    =(int*)  alloc((size_t)NE*4);
  int2*  csr    =(int2*) alloc((size_t)NE*8);
  unsigned* W3  =(unsigned*)alloc((size_t)16*24*18*4);
  unsigned* A   =(unsigned*)alloc((size_t)NN*AW*4 + 1024);  // bf16 rows, 640B line-aligned
  float* h1     =(float*)alloc((size_t)NN*TT*HID*4);
  unsigned* h2p =(unsigned*)alloc((size_t)NN*144*4);        // packed fp16 h2 [n][t][24]

  const int GN=(NN+255)/256, GE=(NE+255)/256;
  const int GMM=(NN+63)/64;              // 64 nodes/block
  const int GAGG=(NN*64+255)/256;        // 1 wave/node
  const int GGRU=(NN+63)/64;             // 64 nodes/block, 16 waves

  k_setup  <<<GN,256,0,stream>>>(cnt,Wih,Whh,W3);
  k_cnt    <<<GE,256,0,stream>>>(ei,cnt,pos);
  k_partA  <<<NB,256,0,stream>>>(cnt,bsum);
  k_midB   <<<1,256,0,stream>>>(bsum,bpre,offs);
  k_offsC  <<<NB,256,0,stream>>>(cnt,bpre,offs);
  k_scatter<<<GE,256,0,stream>>>(ei,ew,offs,pos,csr);
  k_deg    <<<GN,256,0,stream>>>(csr,offs,dis);
  k_normE  <<<GE,256,0,stream>>>(csr,dis);

  // layer 0 -> h1 (fp32, needed as mm1 input + residual)
  k_mm0<<<GMM,256,0,stream>>>(x_seq, W0, A);
  k_agg<<<GAGG,256,0,stream>>>(A,b0,g0,be0,nullptr,h1,nullptr,offs,csr,dis);
  // layer 1 -> h2 packed fp16 (feeds GRU directly; resid = h1)
  k_mm1<<<GMM,256,0,stream>>>(h1, W1, A);
  k_agg<<<GAGG,256,0,stream>>>(A,b1,g1,be1,h1,nullptr,h2p,offs,csr,dis);
  // fused GRU v6 (16 waves, 100% thread occupancy) + classifier
  k_gruF6<<<GGRU,1024,0,stream>>>(h2p, W3, bih,bhh, Wc1,bc1,Wc2,bc2, outp);
}

// Round 14
// 603.956 us; speedup vs baseline: 1.0169x; 1.0169x over previous
//
#include <hip/hip_runtime.h>
#include <hip/hip_fp16.h>
#include <math.h>

#define NN 50000
#define NE 800000
#define TT 6
#define HID 48
#define NB 196   // (NN+255)/256
#define XS 28    // node-major LDS row stride in u32 (112B, 16B-aligned, (7*lane+c)%8 quad-conflict-free)
#define AW 160   // A row stride in u32: 640B = 5 x 128B cachelines, every row line-aligned

__device__ __forceinline__ float sigmoidf_(float x){ return 1.0f/(1.0f+__expf(-x)); }
__device__ __forceinline__ float tanhf_(float x){
  float xc = fminf(fmaxf(x,-15.f),15.f);
  float t = __expf(2.f*xc);
  return (t-1.f)/(t+1.f);
}
__device__ __forceinline__ unsigned f2bf(float x){
  unsigned u = __float_as_uint(x);
  return (u + 0x7fffu + ((u>>16)&1u)) >> 16;   // RNE to bf16
}
__device__ __forceinline__ unsigned pack2(float a, float b){
  return f2bf(a) | (f2bf(b)<<16);
}
__device__ __forceinline__ float bflo(unsigned u){ return __uint_as_float(u<<16); }
__device__ __forceinline__ float bfhi(unsigned u){ return __uint_as_float(u & 0xffff0000u); }
__device__ __forceinline__ unsigned f2h(float x){
  return (unsigned)__half_as_ushort(__float2half(x));   // RNE fp16
}
__device__ __forceinline__ float h2f(unsigned u){
  return __half2float(__ushort_as_half((unsigned short)(u & 0xffffu)));
}
__device__ __forceinline__ unsigned pack2h(float a, float b){   // RNE fp16 pair
  return f2h(a) | (f2h(b)<<16);
}

typedef __fp16 h2t __attribute__((ext_vector_type(2)));

// acc += lo(a)*lo(b) + hi(a)*hi(b), fp32 accumulate
__device__ __forceinline__ float dot2f(unsigned a, unsigned b, float c){
#if __has_builtin(__builtin_amdgcn_fdot2)
  return __builtin_amdgcn_fdot2(__builtin_bit_cast(h2t, a), __builtin_bit_cast(h2t, b), c, false);
#else
  h2t av = __builtin_bit_cast(h2t, a), bv = __builtin_bit_cast(h2t, b);
  return c + (float)av[0]*(float)bv[0] + (float)av[1]*(float)bv[1];
#endif
}

struct U3 { unsigned x,y,z; };

// 256-thread inclusive block scan (4 waves of 64)
__device__ __forceinline__ int block_scan_incl(int x, int* wsum){
  int lane = threadIdx.x & 63, w = threadIdx.x >> 6;
  int v = x;
#pragma unroll
  for(int d=1; d<64; d<<=1){
    int u = __shfl_up(v, d, 64);
    if(lane >= d) v += u;
  }
  if(lane==63) wsum[w] = v;
  __syncthreads();
  int add = 0;
#pragma unroll
  for(int k=0;k<3;k++) if(w>k) add += wsum[k];
  return v + add;
}

// ---------------- setup: cnt init + GRU weight repack (fp16 pairs along k) ----------------
// W2 [12 w][24 k2][24 c] u32: wave w owns hidden features 4w..4w+3.
//   c<12 : h-side (Whh), cc=c:   cc<4 -> r-row (4w+cc), cc<8 -> z-row (48+4w+cc-4), else n-row (96+4w+cc-8)
//   c>=12: x-side (Wih), cc=c-12, same row map.
__global__ __launch_bounds__(256) void k_setup(int* cnt,
                                               const float* __restrict__ Wih, const float* __restrict__ Whh,
                                               unsigned* W2){
  int i = blockIdx.x*256+threadIdx.x;
  if(i<NN) cnt[i]=0;
  if(i < 12*24*24){
    int w = i/576, r = i%576;
    int k2 = r/24, c = r%24;
    int cc = (c<12)? c : (c-12);
    int row = (cc<4) ? (w*4 + cc) : (cc<8) ? (48 + w*4 + cc-4) : (96 + w*4 + cc-8);
    const float* Wsrc = (c<12)? Whh : Wih;
    W2[i] = pack2h(Wsrc[row*48 + 2*k2], Wsrc[row*48 + 2*k2 + 1]);
  }
}

// single atomic per edge: rank within destination bucket
__global__ __launch_bounds__(256) void k_cnt(const int* __restrict__ ei, int* cnt, int* pos){
  int e = blockIdx.x*256+threadIdx.x;
  if(e<NE){
    int c = ei[NE+e];
    pos[e] = atomicAdd(&cnt[c], 1);
  }
}

// phase A: per-block sums of cnt
__global__ __launch_bounds__(256) void k_partA(const int* __restrict__ cnt, int* bsum){
  __shared__ int wsum[4];
  int i = blockIdx.x*256+threadIdx.x;
  int x = (i<NN)? cnt[i] : 0;
  int lane = threadIdx.x & 63, w = threadIdx.x >> 6;
  int v = x;
#pragma unroll
  for(int m=32;m>=1;m>>=1) v += __shfl_xor(v, m, 64);
  if(lane==0) wsum[w]=v;
  __syncthreads();
  if(threadIdx.x==0) bsum[blockIdx.x] = wsum[0]+wsum[1]+wsum[2]+wsum[3];
}

// phase B: exclusive scan of 196 block sums
__global__ __launch_bounds__(256) void k_midB(const int* __restrict__ bsum, int* bpre, int* offs){
  __shared__ int wsum[4];
  int t = threadIdx.x;
  int x = (t<NB)? bsum[t] : 0;
  int incl = block_scan_incl(x, wsum);
  if(t<NB) bpre[t] = incl - x;
  if(t==255) offs[NN] = incl;   // total
}

// phase C: per-block exclusive scan of cnt + bpre -> offs
__global__ __launch_bounds__(256) void k_offsC(const int* __restrict__ cnt, const int* __restrict__ bpre,
                                               int* offs){
  __shared__ int wsum[4];
  int i = blockIdx.x*256+threadIdx.x;
  int x = (i<NN)? cnt[i] : 0;
  int incl = block_scan_incl(x, wsum);
  if(i<NN) offs[i] = bpre[blockIdx.x] + incl - x;
}

// atomic-free scatter: csr[offs[c]+pos[e]] = (row, ew)
__global__ __launch_bounds__(256) void k_scatter(const int* __restrict__ ei, const float* __restrict__ ew,
                                                 const int* __restrict__ offs, const int* __restrict__ pos,
                                                 int2* __restrict__ csr){
  int e = blockIdx.x*256+threadIdx.x;
  if(e<NE){
    int c = ei[NE+e];
    int2 v; v.x = ei[e]; v.y = __float_as_int(ew[e]);
    csr[offs[c]+pos[e]] = v;
  }
}

// deg = 1 + row-sum of ew, dis = rsqrt(deg)  [deg>=1 always]
// r14: 4-deep unrolled edge loop — 4 csr loads in flight per wait in this
// latency-bound serial scan (avg 16 edges/node).
__global__ __launch_bounds__(256) void k_deg(const int2* __restrict__ csr, const int* __restrict__ offs,
                                             float* dis){
  int i = blockIdx.x*256+threadIdx.x;
  if(i<NN){
    float s = 1.f;
    int e0=offs[i], e1=offs[i+1];
    int j=e0;
    for(; j+3<e1; j+=4){
      int2 a=csr[j], b=csr[j+1], c=csr[j+2], d=csr[j+3];
      s += __int_as_float(a.y)+__int_as_float(b.y)+__int_as_float(c.y)+__int_as_float(d.y);
    }
    for(; j<e1; ++j) s += __int_as_float(csr[j].y);
    dis[i] = rsqrtf(s);
  }
}

// patch edge norm in place: y = dis[r]*ew   (dis[c] factored out in k_agg)
// r14: 2 edges per thread via int4 (csr 16B-aligned, NE even) — half the
// instructions on a pure streaming pass.
__global__ __launch_bounds__(256) void k_normE(int2* __restrict__ csr, const float* __restrict__ dis){
  int j = blockIdx.x*256+threadIdx.x;    // pair index
  if(j < NE/2){
    int4 v = reinterpret_cast<int4*>(csr)[j];
    v.y = __float_as_int(dis[v.x]*__int_as_float(v.y));
    v.w = __float_as_int(dis[v.z]*__int_as_float(v.w));
    reinterpret_cast<int4*>(csr)[j] = v;
  }
}

// ---------------- layer-0 matmul: wave = feature slice (uniform), lane = node ----------------
// t-OUTER loop (r8 win): per-wave L1 window 4 KB vs 24 KB.
// A row per node = AW=160 words (640B, line-aligned); data in words 0..143.
__global__ __launch_bounds__(256) void k_mm0(const float* __restrict__ X, const float* __restrict__ W,
                                             unsigned* __restrict__ A){
  int s = __builtin_amdgcn_readfirstlane(threadIdx.x>>6);   // 0..3, wave-uniform
  int n = blockIdx.x*64 + (threadIdx.x&63);
  if(n>=NN) return;
  const float* xb = X + (long long)n*64;
  const float* wb = W + 12*s;
  float acc[TT][12];
#pragma unroll
  for(int t=0;t<TT;t++)
#pragma unroll
    for(int j=0;j<12;j++) acc[t][j]=0.f;
#pragma unroll
  for(int t=0;t<TT;t++){                 // full unroll: acc[t] constant-indexed
    const float* xt = xb + (long long)t*NN*64;
#pragma unroll 2
    for(int k4=0;k4<16;k4++){
      float4 xv = *reinterpret_cast<const float4*>(xt + 4*k4);
#pragma unroll
      for(int q=0;q<4;q++){
        const float* wr = wb + (4*k4+q)*HID;
        float w[12];
#pragma unroll
        for(int j=0;j<12;j++) w[j]=wr[j];   // uniform addr -> s_load
        float xs = (&xv.x)[q];
#pragma unroll
        for(int j=0;j<12;j++) acc[t][j] = fmaf(xs, w[j], acc[t][j]);
      }
    }
  }
  unsigned buf[36];
#pragma unroll
  for(int j=0;j<12;j++){
    buf[3*j  ]=pack2(acc[0][j],acc[1][j]);
    buf[3*j+1]=pack2(acc[2][j],acc[3][j]);
    buf[3*j+2]=pack2(acc[4][j],acc[5][j]);
  }
  uint4* o4 = reinterpret_cast<uint4*>(A + (long long)n*AW + 36*s);
#pragma unroll
  for(int q=0;q<9;q++) o4[q] = make_uint4(buf[4*q],buf[4*q+1],buf[4*q+2],buf[4*q+3]);
}

// ---------------- layer-1 matmul (K=48), input fp32 [n][t][48], t-outer ----------------
__global__ __launch_bounds__(256) void k_mm1(const float* __restrict__ X, const float* __restrict__ W,
                                             unsigned* __restrict__ A){
  int s = __builtin_amdgcn_readfirstlane(threadIdx.x>>6);
  int n = blockIdx.x*64 + (threadIdx.x&63);
  if(n>=NN) return;
  const float* xb = X + (long long)n*(TT*HID);
  const float* wb = W + 12*s;
  float acc[TT][12];
#pragma unroll
  for(int t=0;t<TT;t++)
#pragma unroll
    for(int j=0;j<12;j++) acc[t][j]=0.f;
#pragma unroll
  for(int t=0;t<TT;t++){                 // full unroll: acc[t] constant-indexed
    const float* xt = xb + t*HID;
#pragma unroll 2
    for(int k4=0;k4<12;k4++){
      float4 xv = *reinterpret_cast<const float4*>(xt + 4*k4);
#pragma unroll
      for(int q=0;q<4;q++){
        const float* wr = wb + (4*k4+q)*HID;
        float w[12];
#pragma unroll
        for(int j=0;j<12;j++) w[j]=wr[j];
        float xs = (&xv.x)[q];
#pragma unroll
        for(int j=0;j<12;j++) acc[t][j] = fmaf(xs, w[j], acc[t][j]);
      }
    }
  }
  unsigned buf[36];
#pragma unroll
  for(int j=0;j<12;j++){
    buf[3*j  ]=pack2(acc[0][j],acc[1][j]);
    buf[3*j+1]=pack2(acc[2][j],acc[3][j]);
    buf[3*j+2]=pack2(acc[4][j],acc[5][j]);
  }
  uint4* o4 = reinterpret_cast<uint4*>(A + (long long)n*AW + 36*s);
#pragma unroll
  for(int q=0;q<9;q++) o4[q] = make_uint4(buf[4*q],buf[4*q+1],buf[4*q+2],buf[4*q+3]);
}

// ---------------- CSR aggregation (bf16 gather) + bias + LN + ReLU (+resid)
// Scalarized wave-uniform path (r11). A rows 640B line-aligned (r12).
// out   : optional fp32 [n][t][48] output (layer 0 -> h1, needed for resid+mm1)
// out_pk: optional packed-fp16 [n][t][24 u32] output (layer 1 -> h2p, feeds GRU directly)
__global__ __launch_bounds__(256) void k_agg(const unsigned* __restrict__ A, const float* __restrict__ bias,
                                             const float* __restrict__ gain, const float* __restrict__ beta,
                                             const float* __restrict__ resid, float* __restrict__ out,
                                             unsigned* __restrict__ out_pk,
                                             const int* __restrict__ offs, const int2* __restrict__ csr,
                                             const float* __restrict__ dis){
  int wid = (int)((blockIdx.x*256+threadIdx.x)>>6);
  wid = __builtin_amdgcn_readfirstlane(wid);            // wave-uniform -> scalar
  int lane = threadIdx.x & 63;
  if(wid>=NN) return;
  const bool act = lane<HID;
  const int f = act? lane : (HID-1);
  const unsigned* Arow = A + 3*f;                       // SGPR base + per-lane const
  float dn = dis[wid];                                  // scalar load
  float acc[TT];
  {
    U3 v = *reinterpret_cast<const U3*>(Arow + (long long)wid*AW);
    acc[0]=dn*bflo(v.x); acc[1]=dn*bfhi(v.x);
    acc[2]=dn*bflo(v.y); acc[3]=dn*bfhi(v.y);
    acc[4]=dn*bflo(v.z); acc[5]=dn*bfhi(v.z);
  }
  int e0=offs[wid], e1=offs[wid+1];                     // scalar loads
  int e=e0;
  for(; e+3<e1; e+=4){
    int2 i0=csr[e], i1=csr[e+1], i2=csr[e+2], i3=csr[e+3];   // scalar s_loads
    U3 d0 = *reinterpret_cast<const U3*>(Arow + (long long)i0.x*AW);
    U3 d1 = *reinterpret_cast<const U3*>(Arow + (long long)i1.x*AW);
    U3 d2 = *reinterpret_cast<const U3*>(Arow + (long long)i2.x*AW);
    U3 d3 = *reinterpret_cast<const U3*>(Arow + (long long)i3.x*AW);
    float n0=__int_as_float(i0.y), n1=__int_as_float(i1.y);
    float n2=__int_as_float(i2.y), n3=__int_as_float(i3.y);
    acc[0]=fmaf(n0,bflo(d0.x),acc[0]); acc[1]=fmaf(n0,bfhi(d0.x),acc[1]);
    acc[2]=fmaf(n0,bflo(d0.y),acc[2]); acc[3]=fmaf(n0,bfhi(d0.y),acc[3]);
    acc[4]=fmaf(n0,bflo(d0.z),acc[4]); acc[5]=fmaf(n0,bfhi(d0.z),acc[5]);
    acc[0]=fmaf(n1,bflo(d1.x),acc[0]); acc[1]=fmaf(n1,bfhi(d1.x),acc[1]);
    acc[2]=fmaf(n1,bflo(d1.y),acc[2]); acc[3]=fmaf(n1,bfhi(d1.y),acc[3]);
    acc[4]=fmaf(n1,bflo(d1.z),acc[4]); acc[5]=fmaf(n1,bfhi(d1.z),acc[5]);
    acc[0]=fmaf(n2,bflo(d2.x),acc[0]); acc[1]=fmaf(n2,bfhi(d2.x),acc[1]);
    acc[2]=fmaf(n2,bflo(d2.y),acc[2]); acc[3]=fmaf(n2,bfhi(d2.y),acc[3]);
    acc[4]=fmaf(n2,bflo(d2.z),acc[4]); acc[5]=fmaf(n2,bfhi(d2.z),acc[5]);
    acc[0]=fmaf(n3,bflo(d3.x),acc[0]); acc[1]=fmaf(n3,bfhi(d3.x),acc[1]);
    acc[2]=fmaf(n3,bflo(d3.y),acc[2]); acc[3]=fmaf(n3,bfhi(d3.y),acc[3]);
    acc[4]=fmaf(n3,bflo(d3.z),acc[4]); acc[5]=fmaf(n3,bfhi(d3.z),acc[5]);
  }
  for(; e<e1; ++e){
    int2 i0=csr[e];
    U3 d0 = *reinterpret_cast<const U3*>(Arow + (long long)i0.x*AW);
    float n0=__int_as_float(i0.y);
    acc[0]=fmaf(n0,bflo(d0.x),acc[0]); acc[1]=fmaf(n0,bfhi(d0.x),acc[1]);
    acc[2]=fmaf(n0,bflo(d0.y),acc[2]); acc[3]=fmaf(n0,bfhi(d0.y),acc[3]);
    acc[4]=fmaf(n0,bflo(d0.z),acc[4]); acc[5]=fmaf(n0,bfhi(d0.z),acc[5]);
  }
  float bb = bias[f], gg = gain[f], be = beta[f];
  const float rn = 1.0f/HID;
#pragma unroll
  for(int t=0;t<TT;t++){
    float val = fmaf(acc[t], dn, bb);    // final *dn fold
    float v = act? val : 0.f;
    float s = v, s2 = v*v;
#pragma unroll
    for(int m=32;m>=1;m>>=1){
      s  += __shfl_xor(s,  m, 64);
      s2 += __shfl_xor(s2, m, 64);
    }
    float mu  = s*rn;
    float var = fmaxf(s2*rn - mu*mu, 0.f);
    float y = (val-mu)*rsqrtf(var+1e-5f)*gg + be;
    y = fmaxf(y, 0.f);
    long long oidx = (long long)wid*(TT*HID) + t*HID + f;
    if(resid) y += resid[oidx];
    if(out){
      if(act) out[oidx] = y;
    }
    if(out_pk){
      float yn = __shfl_xor(y, 1, 64);   // pair feature f^1
      if(act && !(lane&1))
        out_pk[(long long)wid*144 + t*24 + (lane>>1)] = pack2h(y, yn);
    }
  }
}

// ---------------- fused GRU v5 (r12 proven best): node-major LDS rows + pure-SMEM k-loops ----
// block: 64 nodes, 768 threads = 12 waves. Wave w owns hidden features 4w..4w+3 (12 gate rows).
// x input PRE-PACKED fp16 pairs [n][t][24 u32] (written by layer-1 k_agg).
__global__ __launch_bounds__(768) void k_gruF5(const unsigned* __restrict__ Xp,  // h2 packed [n][144] u32
                                               const unsigned* __restrict__ W2, // [12][24][24] u32
                                               const float* __restrict__ bih, const float* __restrict__ bhh,
                                               const float* __restrict__ Wc1, const float* __restrict__ bc1,
                                               const float* __restrict__ Wc2, const float* __restrict__ bc2,
                                               float* __restrict__ out){
  __shared__ __align__(16) unsigned xall[TT*64*XS];   // 42 KB
  __shared__ __align__(16) unsigned hb[2][64*XS];     // 14 KB
  int tid = threadIdx.x;
  int wv = __builtin_amdgcn_readfirstlane(tid>>6);   // 0..11, uniform
  int lane = tid & 63;
  int f0 = wv*4;
  long long n = (long long)blockIdx.x*64 + lane;

  // stage x: thread (nd,q) copies node nd's uint2 chunk q for all 6 t; LDS write at
  // pair-bank (nd*14+q)%16 — ~2-way (free).
  {
    int nd = tid/12, q = tid-12*nd;
    long long g = (long long)blockIdx.x*64+nd; if(g>NN-1) g=NN-1;
    const unsigned* xs = Xp + g*144 + 2*q;
#pragma unroll
    for(int t=0;t<TT;t++){
      uint2 v = *reinterpret_cast<const uint2*>(xs + t*24);
      *reinterpret_cast<uint2*>(&xall[t*64*XS + nd*XS + 2*q]) = v;
    }
  }
  for(int i=tid;i<64*XS;i+=768) hb[0][i]=0u;

  float rbi[4], zbi[4], nbi[4], rbh[4], zbh[4], nbh[4], hprev[4];
#pragma unroll
  for(int j=0;j<4;j++){
    rbi[j]=bih[f0+j]; zbi[j]=bih[48+f0+j]; nbi[j]=bih[96+f0+j];
    rbh[j]=bhh[f0+j]; zbh[j]=bhh[48+f0+j]; nbh[j]=bhh[96+f0+j];
    hprev[j]=0.f;
  }
  __syncthreads();   // xall + hb[0] ready

  int cur=0;
#pragma unroll
  for(int tp=0; tp<2; tp++){
    // ---- phase 1: gi for steps 3tp..3tp+2 (x-side only, barrier-free) ----
    unsigned gi[18];
#pragma unroll
    for(int s=0;s<3;s++){
      float a[12];
#pragma unroll
      for(int j=0;j<4;j++){ a[j]=rbi[j]; a[4+j]=zbi[j]; a[8+j]=nbi[j]; }
      const uint4* xrow = reinterpret_cast<const uint4*>(&xall[(tp*3+s)*64*XS + lane*XS]);
      const unsigned* wbx = W2 + wv*24*24 + 12;   // x-slice base
#pragma unroll 2
      for(int c6=0;c6<6;c6++){
        uint4 hq = xrow[c6];                      // ds_read_b128, conflict-free
        unsigned xv_[4] = {hq.x, hq.y, hq.z, hq.w};
#pragma unroll
        for(int j4=0;j4<4;j4++){
          const unsigned* wp = wbx + (4*c6+j4)*24;
          unsigned ws[12];
#pragma unroll
          for(int q=0;q<12;q++) ws[q]=wp[q];      // uniform -> s_load
#pragma unroll
          for(int c=0;c<12;c++) a[c]=dot2f(xv_[j4], ws[c], a[c]);
        }
      }
#pragma unroll
      for(int m=0;m<6;m++) gi[s*6+m]=pack2h(a[2*m], a[2*m+1]);
    }
    // ---- phase 2: 3 recurrence steps (h-weights sK$-resident, pure-SMEM k-loop) ----
#pragma unroll
    for(int s=0;s<3;s++){
      float acc[12];
#pragma unroll
      for(int j=0;j<4;j++){ acc[j]=rbh[j]; acc[4+j]=zbh[j]; acc[8+j]=nbh[j]; }
      const uint4* hrow = reinterpret_cast<const uint4*>(&hb[cur][lane*XS]);
      const unsigned* wbh = W2 + wv*24*24;        // h-slice base
#pragma unroll 2
      for(int c6=0;c6<6;c6++){
        uint4 hq = hrow[c6];                      // ds_read_b128, conflict-free
        unsigned hv_[4] = {hq.x, hq.y, hq.z, hq.w};
#pragma unroll
        for(int j4=0;j4<4;j4++){
          const unsigned* wp = wbh + (4*c6+j4)*24;
          unsigned ws[12];
#pragma unroll
          for(int q=0;q<12;q++) ws[q]=wp[q];      // uniform -> s_load
#pragma unroll
          for(int c=0;c<12;c++) acc[c]=dot2f(hv_[j4], ws[c], acc[c]);
        }
      }
      float hn[4];
#pragma unroll
      for(int j=0;j<4;j++){
        unsigned pr=gi[s*6+(j>>1)], pz=gi[s*6+2+(j>>1)], pn=gi[s*6+4+(j>>1)];
        float gir=(j&1)? h2f(pr>>16):h2f(pr);
        float giz=(j&1)? h2f(pz>>16):h2f(pz);
        float gin=(j&1)? h2f(pn>>16):h2f(pn);
        float r  = sigmoidf_(acc[j]+gir);
        float zg = sigmoidf_(acc[4+j]+giz);
        float ng = tanhf_(gin + r*acc[8+j]);
        float hv = (1.f-zg)*ng + zg*hprev[j];
        hprev[j]=hv; hn[j]=hv;
      }
      *reinterpret_cast<uint2*>(&hb[cur^1][lane*XS + 2*wv]) =
          make_uint2(pack2h(hn[0],hn[1]), pack2h(hn[2],hn[3]));
      __syncthreads();   // next buffer fully written
      cur^=1;
    }
  }

  // classifier epilogue: wave 0 covers the block's 64 nodes
  if(wv==0 && n<NN){
    unsigned hh[24];
    {
      const uint4* hrow = reinterpret_cast<const uint4*>(&hb[cur][lane*XS]);
#pragma unroll
      for(int c6=0;c6<6;c6++){
        uint4 v = hrow[c6];
        hh[4*c6]=v.x; hh[4*c6+1]=v.y; hh[4*c6+2]=v.z; hh[4*c6+3]=v.w;
      }
    }
    float hv[24];
#pragma unroll
    for(int j=0;j<24;j++) hv[j]=bc1[j];
#pragma unroll 2
    for(int k2=0;k2<24;k2++){
      float hk0 = h2f(hh[k2]), hk1 = h2f(hh[k2]>>16);
      const float* w0 = Wc1 + (2*k2)*24;     // uniform -> s_load
      const float* w1 = Wc1 + (2*k2+1)*24;
#pragma unroll
      for(int j=0;j<24;j++) hv[j] = fmaf(hk0, w0[j], hv[j]);
#pragma unroll
      for(int j=0;j<24;j++) hv[j] = fmaf(hk1, w1[j], hv[j]);
    }
    float l0=bc2[0], l1=bc2[1];
#pragma unroll
    for(int j=0;j<24;j++){
      float a = fmaxf(hv[j],0.f);
      l0 = fmaf(a, Wc2[2*j],   l0);
      l1 = fmaf(a, Wc2[2*j+1], l1);
    }
    reinterpret_cast<float2*>(out)[n] = make_float2(l0,l1);
  }
}

static inline size_t al256(size_t x){ return (x+255)&~(size_t)255; }

extern "C" void kernel_launch(void* const* d_in, const int* in_sizes, int n_in,
                              void* d_out, int out_size, void* d_ws, size_t ws_size,
                              hipStream_t stream){
  const float* x_seq=(const float*)d_in[0];
  const int*   ei   =(const int*)d_in[1];
  const float* ew   =(const float*)d_in[2];
  const float* W0=(const float*)d_in[3];  const float* b0=(const float*)d_in[4];
  const float* g0=(const float*)d_in[5];  const float* be0=(const float*)d_in[6];
  const float* W1=(const float*)d_in[7];  const float* b1=(const float*)d_in[8];
  const float* g1=(const float*)d_in[9];  const float* be1=(const float*)d_in[10];
  const float* Wih=(const float*)d_in[11];const float* Whh=(const float*)d_in[12];
  const float* bih=(const float*)d_in[13];const float* bhh=(const float*)d_in[14];
  const float* Wc1=(const float*)d_in[15];const float* bc1=(const float*)d_in[16];
  const float* Wc2=(const float*)d_in[17];const float* bc2=(const float*)d_in[18];
  float* outp=(float*)d_out;

  char* p=(char*)d_ws; size_t off=0;
  auto alloc=[&](size_t bytes)->void*{ void* r=p+off; off=al256(off+bytes); return r; };
  float* dis    =(float*)alloc((size_t)NN*4);
  int*   cnt    =(int*)  alloc((size_t)NN*4);
  int*   offs   =(int*)  alloc((size_t)(NN+1)*4);
  int*   bsum   =(int*)  alloc((size_t)NB*4);
  int*   bpre   =(int*)  alloc((size_t)NB*4);
  int*   pos    =(int*)  alloc((size_t)NE*4);
  int2*  csr    =(int2*) alloc((size_t)NE*8);
  unsigned* W2  =(unsigned*)alloc((size_t)12*24*24*4);
  unsigned* A   =(unsigned*)alloc((size_t)NN*AW*4 + 1024);  // bf16 rows, 640B line-aligned
  float* h1     =(float*)alloc((size_t)NN*TT*HID*4);
  unsigned* h2p =(unsigned*)alloc((size_t)NN*144*4);        // packed fp16 h2 [n][t][24]

  const int GN=(NN+255)/256, GE=(NE+255)/256, GE2=(NE/2+255)/256;
  const int GMM=(NN+63)/64;              // 64 nodes/block
  const int GAGG=(NN*64+255)/256;        // 1 wave/node
  const int GGRU=(NN+63)/64;             // 64 nodes/block, 12 waves

  k_setup  <<<GN,256,0,stream>>>(cnt,Wih,Whh,W2);
  k_cnt    <<<GE,256,0,stream>>>(ei,cnt,pos);
  k_partA  <<<NB,256,0,stream>>>(cnt,bsum);
  k_midB   <<<1,256,0,stream>>>(bsum,bpre,offs);
  k_offsC  <<<NB,256,0,stream>>>(cnt,bpre,offs);
  k_scatter<<<GE,256,0,stream>>>(ei,ew,offs,pos,csr);
  k_deg    <<<GN,256,0,stream>>>(csr,offs,dis);
  k_normE  <<<GE2,256,0,stream>>>(csr,dis);

  // layer 0 -> h1 (fp32, needed as mm1 input + residual)
  k_mm0<<<GMM,256,0,stream>>>(x_seq, W0, A);
  k_agg<<<GAGG,256,0,stream>>>(A,b0,g0,be0,nullptr,h1,nullptr,offs,csr,dis);
  // layer 1 -> h2 packed fp16 (feeds GRU directly; resid = h1)
  k_mm1<<<GMM,256,0,stream>>>(h1, W1, A);
  k_agg<<<GAGG,256,0,stream>>>(A,b1,g1,be1,h1,nullptr,h2p,offs,csr,dis);
  // fused GRU v5 (r12 proven) + classifier
  k_gruF5<<<GGRU,768,0,stream>>>(h2p, W2, bih,bhh, Wc1,bc1,Wc2,bc2, outp);
}